// Round 11
// baseline (129.341 us; speedup 1.0000x reference)
//
#include <hip/hip_runtime.h>

#define NN 2048
#define DD 64
#define C1 0.36067376f  // 2/sqrt(D) * log2(e)
#define C1H 0.18033688f // C1/2

typedef _Float16 h8 __attribute__((ext_vector_type(8)));
typedef _Float16 h4 __attribute__((ext_vector_type(4)));
typedef float f32x16 __attribute__((ext_vector_type(16)));

union H8U4 { h8 v; unsigned u[4]; };

static __device__ inline float max3f(float a, float b, float c) {
    return fmaxf(fmaxf(a, b), c);     // clang fuses to v_max3_f32
}

// v_permlane32_swap_b32 semantics (gfx950, verified on HW in R9):
//   swap(a,b): r[0] = {a[0:31] | b[0:31]};  r[1] = {a[32:63] | b[32:63]}
static __device__ inline float ph_max(float v) {
    unsigned u; __builtin_memcpy(&u, &v, 4);
    auto rr = __builtin_amdgcn_permlane32_swap(u, u, false, false);
    unsigned r0 = rr[0], r1 = rr[1];
    float a, b; __builtin_memcpy(&a, &r0, 4); __builtin_memcpy(&b, &r1, 4);
    return fmaxf(a, b);
}
static __device__ inline float ph_sum(float v) {
    unsigned u; __builtin_memcpy(&u, &v, 4);
    auto rr = __builtin_amdgcn_permlane32_swap(u, u, false, false);
    unsigned r0 = rr[0], r1 = rr[1];
    float a, b; __builtin_memcpy(&a, &r0, 4); __builtin_memcpy(&b, &r1, 4);
    return a + b;
}

// ---- prep: frag-major swizzles so the main loop is pure coalesced loads ----
// Ks[bh][jj][c][lh][ln]{8}  = K[32jj+ln][16c+8lh+0..7]          (A-frag order)
// Vs[bh][jj][o][c][lh][ln]{8}= V[32jj+16c+8lh+j][32o+ln]        (V^T A-frag order)
// hk[bh][n] = -C1H*||k_n||^2   (NEGATED: used directly as QK accumulator init)
__global__ __launch_bounds__(64) void prep(const float* __restrict__ k,
                                           const float* __restrict__ v,
                                           _Float16* __restrict__ Ks,
                                           _Float16* __restrict__ Vs,
                                           float* __restrict__ hk) {
    __shared__ _Float16 T[32][72];
    const int jj = blockIdx.x, bh = blockIdx.y, lane = threadIdx.x;
    const int ln = lane & 31, lh = lane >> 5;
    const size_t ibase = (size_t)bh * NN * DD + (size_t)jj * 32 * DD;

    { // K frags + row sumsq (lh halves cover complementary d-ranges)
        const float* kr = k + ibase + (size_t)ln * DD;
        float s = 0.f;
#pragma unroll
        for (int c = 0; c < 4; ++c) {
            float4 a = *(const float4*)&kr[16 * c + 8 * lh];
            float4 b = *(const float4*)&kr[16 * c + 8 * lh + 4];
            h8 o = {(_Float16)a.x, (_Float16)a.y, (_Float16)a.z, (_Float16)a.w,
                    (_Float16)b.x, (_Float16)b.y, (_Float16)b.z, (_Float16)b.w};
            *(h8*)&Ks[((size_t)bh * 16384 + jj * 256 + c * 64 + lh * 32 + ln) * 8] = o;
            s += a.x*a.x + a.y*a.y + a.z*a.z + a.w*a.w
               + b.x*b.x + b.y*b.y + b.z*b.z + b.w*b.w;
        }
        s += __shfl_xor(s, 32);
        if (lh == 0) hk[bh * NN + jj * 32 + ln] = s * (-C1H);
    }

    // V tile -> LDS f16 -> transposed frag-major store
#pragma unroll
    for (int t = 0; t < 8; ++t) {
        int f = lane + 64 * t;            // 512 float4 groups = 32 rows x 16
        int row = f >> 4, c4 = (f & 15) * 4;
        float4 a = *(const float4*)&v[ibase + (size_t)row * DD + c4];
        h4 hv = {(_Float16)a.x, (_Float16)a.y, (_Float16)a.z, (_Float16)a.w};
        *(h4*)&T[row][c4] = hv;
    }
    __syncthreads();
#pragma unroll
    for (int oc = 0; oc < 4; ++oc) {
        int o = oc >> 1, c = oc & 1;
        h8 r;
#pragma unroll
        for (int jx = 0; jx < 8; ++jx) r[jx] = T[16 * c + 8 * lh + jx][32 * o + ln];
        *(h8*)&Vs[((size_t)bh * 16384 + jj * 256 + o * 128 + c * 64 + lh * 32 + ln) * 8] = r;
    }
}

// ---- main: flash RBF, key-split-2, QK/softmax pipeline, bias-in-accumulator --
// Per tile: S = MFMA(K, C1*Q) with accumulator INITIALIZED to -C1H*||k||^2, so
// x = S directly (no per-tile fmaf pass; hk latency prefetched 2-deep with K).
// Block = 2 waves on one 32-row q-tile; wave0 keys [0,ceil(T/2)), wave1 rest.
// REGISTER CLASS: 2 waves/SIMD (R3/R5: forcing more spills). Sentinels:
// WRITE_SIZE 16.4 MB, VGPR ~90.
__global__ __launch_bounds__(128, 2) void rbf_attn(
    const float* __restrict__ q, const _Float16* __restrict__ Ks,
    const _Float16* __restrict__ Vs, const float* __restrict__ hk,
    float* __restrict__ out)
{
    __shared__ float sm[64][34];         // wave1: O (32 f32/lane) + l + m
    const int tid = threadIdx.x;
    const int bh = blockIdx.x;
    const int qt = 63 - (int)blockIdx.y; // q-tile (32 rows); LPT: heavy first
    const int wv = tid >> 6, lane = tid & 63;
    const int ln = lane & 31, lh = lane >> 5;
    const int qrow = qt * 32 + ln;
    const size_t fbase = (size_t)bh * NN * DD;

    // Q B-frags pre-scaled by C1 (folds the logit scale into the MFMA)
    h8 qf[4];
    {
        const float* qr = q + fbase + (size_t)qrow * DD;
#pragma unroll
        for (int c = 0; c < 4; ++c) {
            float4 a = *(const float4*)&qr[16 * c + 8 * lh];
            float4 b = *(const float4*)&qr[16 * c + 8 * lh + 4];
            qf[c] = h8{(_Float16)(C1 * a.x), (_Float16)(C1 * a.y),
                       (_Float16)(C1 * a.z), (_Float16)(C1 * a.w),
                       (_Float16)(C1 * b.x), (_Float16)(C1 * b.y),
                       (_Float16)(C1 * b.z), (_Float16)(C1 * b.w)};
        }
    }

    const _Float16* Ksb = Ks + (size_t)bh * 131072;
    const _Float16* Vsb = Vs + (size_t)bh * 131072;
    const float4* hk4 = (const float4*)(hk + bh * NN);
    const int klq = (lh * 32 + ln) * 8;  // element offset of this lane's frag

    f32x16 O0, O1;
#pragma unroll
    for (int r = 0; r < 16; ++r) { O0[r] = 0.f; O1[r] = 0.f; }
    float lsum = 0.f, mrun = -INFINITY;

    const int T = qt + 1;                // key tiles for this q-tile
    const int half = (T + 1) >> 1;       // wave0 gets ceil (wave1 pays diag mask)
    const int j0 = wv ? half : 0;
    const int j1 = wv ? T : half;

    auto loadKH = [&](int jj, h8 (&kf)[4], float4 (&hr)[4]) {
        const _Float16* kp = Ksb + (size_t)jj * 2048 + klq;
#pragma unroll
        for (int c = 0; c < 4; ++c) kf[c] = *(const h8*)(kp + c * 512);
#pragma unroll
        for (int g = 0; g < 4; ++g) hr[g] = hk4[jj * 8 + g * 2 + lh];
    };

    // S = K.(C1*Q) with C-init = -C1H*||k||^2 per key row -> x = S directly
    auto qk = [&](const h8 (&kf)[4], const float4 (&hr)[4]) {
        f32x16 S;
#pragma unroll
        for (int r = 0; r < 16; ++r) S[r] = ((const float*)&hr[r >> 2])[r & 3];
#pragma unroll
        for (int c = 0; c < 4; ++c)
            S = __builtin_amdgcn_mfma_f32_32x32x16_f16(kf[c], qf[c], S, 0, 0, 0);
        return S;
    };

    // softmax + PV for tile jj, consuming precomputed S (= shifted logits)
    auto smpv = [&](int jj, const f32x16& S) {
        h8 vf[4];
        const _Float16* vp = Vsb + (size_t)jj * 2048 + klq;
#pragma unroll
        for (int oc = 0; oc < 4; ++oc)
            vf[oc] = *(const h8*)(vp + (oc >> 1) * 1024 + (oc & 1) * 512);

        const bool diag = (jj == qt);
        float x[16];
#pragma unroll
        for (int r = 0; r < 16; ++r) {
            float xv = S[r];
            if (diag) {
                int keyloc = (r & 3) + 8 * (r >> 2) + 4 * lh;
                if (keyloc > ln) xv = -INFINITY;
            }
            x[r] = xv;
        }
        // max3-structured reduce (8 ops vs 15)
        float m0 = max3f(x[0], x[1], x[2]);
        float m1 = max3f(x[3], x[4], x[5]);
        float m2 = max3f(x[6], x[7], x[8]);
        float m3 = max3f(x[9], x[10], x[11]);
        float m4 = max3f(x[12], x[13], x[14]);
        float mt = max3f(max3f(m0, m1, m2), fmaxf(m3, m4), x[15]);
        mt = ph_max(mt);
        float mnew = fmaxf(mrun, mt);
        float alpha = __builtin_amdgcn_exp2f(mrun - mnew);
        mrun = mnew;
        float p[16], ps;
#pragma unroll
        for (int r = 0; r < 16; ++r) p[r] = __builtin_amdgcn_exp2f(x[r] - mnew);
        ps = (((p[0] + p[1]) + (p[2] + p[3])) + ((p[4] + p[5]) + (p[6] + p[7])))
           + (((p[8] + p[9]) + (p[10] + p[11])) + ((p[12] + p[13]) + (p[14] + p[15])));
        lsum = fmaf(lsum, alpha, ps);
#pragma unroll
        for (int r = 0; r < 16; ++r) { O0[r] *= alpha; O1[r] *= alpha; }

        unsigned pk[8];
#pragma unroll
        for (int hh = 0; hh < 8; ++hh) {
            auto prr = __builtin_amdgcn_cvt_pkrtz(p[2 * hh], p[2 * hh + 1]);
            unsigned pu; __builtin_memcpy(&pu, &prr, 4);
            pk[hh] = pu;
        }
#pragma unroll
        for (int s = 0; s < 2; ++s) {    // C-frag -> B-frag(P^T), R9-verified
            auto r02 = __builtin_amdgcn_permlane32_swap(pk[4 * s + 0], pk[4 * s + 2],
                                                        false, false);
            auto r13 = __builtin_amdgcn_permlane32_swap(pk[4 * s + 1], pk[4 * s + 3],
                                                        false, false);
            H8U4 pb;
            pb.u[0] = r02[0];
            pb.u[1] = r13[0];
            pb.u[2] = r02[1];
            pb.u[3] = r13[1];
            O0 = __builtin_amdgcn_mfma_f32_32x32x16_f16(vf[s], pb.v, O0, 0, 0, 0);
            O1 = __builtin_amdgcn_mfma_f32_32x32x16_f16(vf[2 + s], pb.v, O1, 0, 0, 0);
        }
    };

    // pipelined rotated loop: S double-buffer, K+hk 2-deep prefetch (clamped;
    // tail clamp loads are in-workspace and never consumed)
    if (j0 < j1) {
        h8 kfA[4], kfB[4];
        float4 hrA[4], hrB[4];
        loadKH(j0, kfA, hrA);
        int jp = (j0 + 1 < j1) ? j0 + 1 : j1 - 1;
        loadKH(jp, kfB, hrB);
        f32x16 Sa = qk(kfA, hrA);
        f32x16 Sb;
        int jj = j0;
        while (true) {
            // phase A: S for jj ready in Sa; kfB/hrB hold jj+1 (or clamp)
            Sb = qk(kfB, hrB);                             // next tile's QK
            { int jn = (jj + 2 < j1) ? jj + 2 : j1 - 1; loadKH(jn, kfA, hrA); }
            smpv(jj, Sa);                                  // interleaves w/ QK
            if (++jj >= j1) break;
            // phase B: roles swapped
            Sa = qk(kfA, hrA);
            { int jn = (jj + 2 < j1) ? jj + 2 : j1 - 1; loadKH(jn, kfB, hrB); }
            smpv(jj, Sb);
            if (++jj >= j1) break;
        }
    }

    // merge: wave1 publishes (m,l,O); wave0 flash-combines, normalizes, stores
    if (wv) {
#pragma unroll
        for (int r = 0; r < 16; ++r) { sm[lane][r] = O0[r]; sm[lane][16 + r] = O1[r]; }
        sm[lane][32] = ph_sum(lsum);
        sm[lane][33] = mrun;
    }
    __syncthreads();
    if (!wv) {
        float l0 = ph_sum(lsum);
        float l1 = sm[lane][32];
        float m1 = sm[lane][33];
        float m = fmaxf(mrun, m1);
        float a0 = __builtin_amdgcn_exp2f(mrun - m);
        float a1 = __builtin_amdgcn_exp2f(m1 - m);   // wave1 empty: m1=-inf -> 0
        float lt = l0 * a0 + l1 * a1;
        float inv = 1.f / lt;
        float s0 = a0 * inv, s1 = a1 * inv;
        size_t ro = fbase + (size_t)qrow * DD;
#pragma unroll
        for (int g = 0; g < 4; ++g) {
            float4 o0 = make_float4(O0[4 * g + 0] * s0 + sm[lane][4 * g + 0] * s1,
                                    O0[4 * g + 1] * s0 + sm[lane][4 * g + 1] * s1,
                                    O0[4 * g + 2] * s0 + sm[lane][4 * g + 2] * s1,
                                    O0[4 * g + 3] * s0 + sm[lane][4 * g + 3] * s1);
            *(float4*)&out[ro + 8 * g + 4 * lh] = o0;
            float4 o1 = make_float4(O1[4 * g + 0] * s0 + sm[lane][16 + 4 * g + 0] * s1,
                                    O1[4 * g + 1] * s0 + sm[lane][16 + 4 * g + 1] * s1,
                                    O1[4 * g + 2] * s0 + sm[lane][16 + 4 * g + 2] * s1,
                                    O1[4 * g + 3] * s0 + sm[lane][16 + 4 * g + 3] * s1);
            *(float4*)&out[ro + 32 + 8 * g + 4 * lh] = o1;
        }
    }
}

extern "C" void kernel_launch(void* const* d_in, const int* in_sizes, int n_in,
                              void* d_out, int out_size, void* d_ws, size_t ws_size,
                              hipStream_t stream) {
    (void)in_sizes; (void)n_in; (void)out_size; (void)ws_size;
    const float* q = (const float*)d_in[0];
    const float* k = (const float*)d_in[1];
    const float* v = (const float*)d_in[2];
    float* out = (float*)d_out;

    // ws: [hk 256KB][Ks 8MB f16][Vs 8MB f16]
    float* hk = (float*)d_ws;
    _Float16* Ks = (_Float16*)((char*)d_ws + 262144);
    _Float16* Vs = (_Float16*)((char*)d_ws + 262144 + 8388608);

    prep<<<dim3(64, 32), 64, 0, stream>>>(k, v, Ks, Vs, hk);
    rbf_attn<<<dim3(32, 64), 128, 0, stream>>>(q, Ks, Vs, hk, out);
}

// Round 12
// 127.755 us; speedup vs baseline: 1.0124x; 1.0124x over previous
//
#include <hip/hip_runtime.h>

#define NN 2048
#define DD 64
#define C1 0.36067376f  // 2/sqrt(D) * log2(e)
#define C1H 0.18033688f // C1/2

typedef _Float16 h8 __attribute__((ext_vector_type(8)));
typedef _Float16 h4 __attribute__((ext_vector_type(4)));
typedef float f32x16 __attribute__((ext_vector_type(16)));

union H8U4 { h8 v; unsigned u[4]; };

static __device__ inline float max3f(float a, float b, float c) {
    return fmaxf(fmaxf(a, b), c);     // clang fuses to v_max3_f32
}

// v_permlane32_swap_b32 semantics (gfx950, verified on HW in R9):
//   swap(a,b): r[0] = {a[0:31] | b[0:31]};  r[1] = {a[32:63] | b[32:63]}
static __device__ inline float ph_max(float v) {
    unsigned u; __builtin_memcpy(&u, &v, 4);
    auto rr = __builtin_amdgcn_permlane32_swap(u, u, false, false);
    unsigned r0 = rr[0], r1 = rr[1];
    float a, b; __builtin_memcpy(&a, &r0, 4); __builtin_memcpy(&b, &r1, 4);
    return fmaxf(a, b);
}
static __device__ inline float ph_sum(float v) {
    unsigned u; __builtin_memcpy(&u, &v, 4);
    auto rr = __builtin_amdgcn_permlane32_swap(u, u, false, false);
    unsigned r0 = rr[0], r1 = rr[1];
    float a, b; __builtin_memcpy(&a, &r0, 4); __builtin_memcpy(&b, &r1, 4);
    return a + b;
}

// ---- prep: frag-major swizzles so the main loop is pure coalesced loads ----
// Ks[bh][jj][c][lh][ln]{8}  = K[32jj+ln][16c+8lh+0..7]          (A-frag order)
// Vs[bh][jj][o][c][lh][ln]{8}= V[32jj+16c+8lh+j][32o+ln]        (V^T A-frag order)
// hk[bh][n] = -C1H*||k_n||^2   (NEGATED: used directly as QK accumulator init)
__global__ __launch_bounds__(64) void prep(const float* __restrict__ k,
                                           const float* __restrict__ v,
                                           _Float16* __restrict__ Ks,
                                           _Float16* __restrict__ Vs,
                                           float* __restrict__ hk) {
    __shared__ _Float16 T[32][72];
    const int jj = blockIdx.x, bh = blockIdx.y, lane = threadIdx.x;
    const int ln = lane & 31, lh = lane >> 5;
    const size_t ibase = (size_t)bh * NN * DD + (size_t)jj * 32 * DD;

    { // K frags + row sumsq (lh halves cover complementary d-ranges)
        const float* kr = k + ibase + (size_t)ln * DD;
        float s = 0.f;
#pragma unroll
        for (int c = 0; c < 4; ++c) {
            float4 a = *(const float4*)&kr[16 * c + 8 * lh];
            float4 b = *(const float4*)&kr[16 * c + 8 * lh + 4];
            h8 o = {(_Float16)a.x, (_Float16)a.y, (_Float16)a.z, (_Float16)a.w,
                    (_Float16)b.x, (_Float16)b.y, (_Float16)b.z, (_Float16)b.w};
            *(h8*)&Ks[((size_t)bh * 16384 + jj * 256 + c * 64 + lh * 32 + ln) * 8] = o;
            s += a.x*a.x + a.y*a.y + a.z*a.z + a.w*a.w
               + b.x*b.x + b.y*b.y + b.z*b.z + b.w*b.w;
        }
        s += __shfl_xor(s, 32);
        if (lh == 0) hk[bh * NN + jj * 32 + ln] = s * (-C1H);
    }

    // V tile -> LDS f16 -> transposed frag-major store
#pragma unroll
    for (int t = 0; t < 8; ++t) {
        int f = lane + 64 * t;            // 512 float4 groups = 32 rows x 16
        int row = f >> 4, c4 = (f & 15) * 4;
        float4 a = *(const float4*)&v[ibase + (size_t)row * DD + c4];
        h4 hv = {(_Float16)a.x, (_Float16)a.y, (_Float16)a.z, (_Float16)a.w};
        *(h4*)&T[row][c4] = hv;
    }
    __syncthreads();
#pragma unroll
    for (int oc = 0; oc < 4; ++oc) {
        int o = oc >> 1, c = oc & 1;
        h8 r;
#pragma unroll
        for (int jx = 0; jx < 8; ++jx) r[jx] = T[16 * c + 8 * lh + jx][32 * o + ln];
        *(h8*)&Vs[((size_t)bh * 16384 + jj * 256 + o * 128 + c * 64 + lh * 32 + ln) * 8] = r;
    }
}

// ---- main: flash RBF, key-split-2, full load pipeline + XCD swizzle ----
// 1D grid n=0..2047: bh = (n&7)*4 + ((n>>3)&3), qt = 63-(n>>5). With
// round-robin XCD dispatch each XCD sees only 4 bh slices (2 MB Ks+Vs) ->
// L2-resident instead of L3 (~200 vs ~600 cyc). Bijective; LPT preserved.
// Per phase: qk(next S) -> issue V(jj+1), K/hk(jj+2) -> smpv(jj) consuming
// buffers loaded a FULL PHASE earlier (every load gets >=1 phase of cover).
// Bias-in-accumulator (R11): S init = -C1H||k||^2, qf pre-scaled by C1.
// REGISTER CLASS: 2 waves/SIMD. Sentinels: WRITE_SIZE 16.4 MB, VGPR ~120.
__global__ __launch_bounds__(128, 2) void rbf_attn(
    const float* __restrict__ q, const _Float16* __restrict__ Ks,
    const _Float16* __restrict__ Vs, const float* __restrict__ hk,
    float* __restrict__ out)
{
    __shared__ float sm[64][34];         // wave1: O (32 f32/lane) + l + m
    const int tid = threadIdx.x;
    const int n = blockIdx.x;
    const int bh = (n & 7) * 4 + ((n >> 3) & 3);
    const int qt = 63 - (n >> 5);        // LPT: heavy q-tiles dispatch first
    const int wv = tid >> 6, lane = tid & 63;
    const int ln = lane & 31, lh = lane >> 5;
    const int qrow = qt * 32 + ln;
    const size_t fbase = (size_t)bh * NN * DD;

    // Q B-frags pre-scaled by C1 (folds the logit scale into the MFMA)
    h8 qf[4];
    {
        const float* qr = q + fbase + (size_t)qrow * DD;
#pragma unroll
        for (int c = 0; c < 4; ++c) {
            float4 a = *(const float4*)&qr[16 * c + 8 * lh];
            float4 b = *(const float4*)&qr[16 * c + 8 * lh + 4];
            qf[c] = h8{(_Float16)(C1 * a.x), (_Float16)(C1 * a.y),
                       (_Float16)(C1 * a.z), (_Float16)(C1 * a.w),
                       (_Float16)(C1 * b.x), (_Float16)(C1 * b.y),
                       (_Float16)(C1 * b.z), (_Float16)(C1 * b.w)};
        }
    }

    const _Float16* Ksb = Ks + (size_t)bh * 131072;
    const _Float16* Vsb = Vs + (size_t)bh * 131072;
    const float4* hk4 = (const float4*)(hk + bh * NN);
    const int klq = (lh * 32 + ln) * 8;  // element offset of this lane's frag

    f32x16 O0, O1;
#pragma unroll
    for (int r = 0; r < 16; ++r) { O0[r] = 0.f; O1[r] = 0.f; }
    float lsum = 0.f, mrun = -INFINITY;

    const int T = qt + 1;                // key tiles for this q-tile
    const int half = (T + 1) >> 1;       // wave0 gets ceil (wave1 pays diag mask)
    const int j0 = wv ? half : 0;
    const int j1 = wv ? T : half;

    auto loadKH = [&](int jj, h8 (&kf)[4], float4 (&hr)[4]) {
        const _Float16* kp = Ksb + (size_t)jj * 2048 + klq;
#pragma unroll
        for (int c = 0; c < 4; ++c) kf[c] = *(const h8*)(kp + c * 512);
#pragma unroll
        for (int g = 0; g < 4; ++g) hr[g] = hk4[jj * 8 + g * 2 + lh];
    };
    auto loadV = [&](int jj, h8 (&vf)[4]) {
        const _Float16* vp = Vsb + (size_t)jj * 2048 + klq;
#pragma unroll
        for (int oc = 0; oc < 4; ++oc)
            vf[oc] = *(const h8*)(vp + (oc >> 1) * 1024 + (oc & 1) * 512);
    };

    // S = K.(C1*Q) with C-init = -C1H*||k||^2 per key row -> x = S directly
    auto qk = [&](const h8 (&kf)[4], const float4 (&hr)[4]) {
        f32x16 S;
#pragma unroll
        for (int r = 0; r < 16; ++r) S[r] = ((const float*)&hr[r >> 2])[r & 3];
#pragma unroll
        for (int c = 0; c < 4; ++c)
            S = __builtin_amdgcn_mfma_f32_32x32x16_f16(kf[c], qf[c], S, 0, 0, 0);
        return S;
    };

    // softmax + PV for tile jj, consuming precomputed S and prefetched vf
    auto smpv = [&](int jj, const f32x16& S, const h8 (&vf)[4]) {
        const bool diag = (jj == qt);
        float x[16];
#pragma unroll
        for (int r = 0; r < 16; ++r) {
            float xv = S[r];
            if (diag) {
                int keyloc = (r & 3) + 8 * (r >> 2) + 4 * lh;
                if (keyloc > ln) xv = -INFINITY;
            }
            x[r] = xv;
        }
        float m0 = max3f(x[0], x[1], x[2]);
        float m1 = max3f(x[3], x[4], x[5]);
        float m2 = max3f(x[6], x[7], x[8]);
        float m3 = max3f(x[9], x[10], x[11]);
        float m4 = max3f(x[12], x[13], x[14]);
        float mt = max3f(max3f(m0, m1, m2), fmaxf(m3, m4), x[15]);
        mt = ph_max(mt);
        float mnew = fmaxf(mrun, mt);
        float alpha = __builtin_amdgcn_exp2f(mrun - mnew);
        mrun = mnew;
        float p[16], ps;
#pragma unroll
        for (int r = 0; r < 16; ++r) p[r] = __builtin_amdgcn_exp2f(x[r] - mnew);
        ps = (((p[0] + p[1]) + (p[2] + p[3])) + ((p[4] + p[5]) + (p[6] + p[7])))
           + (((p[8] + p[9]) + (p[10] + p[11])) + ((p[12] + p[13]) + (p[14] + p[15])));
        lsum = fmaf(lsum, alpha, ps);
#pragma unroll
        for (int r = 0; r < 16; ++r) { O0[r] *= alpha; O1[r] *= alpha; }

        unsigned pk[8];
#pragma unroll
        for (int hh = 0; hh < 8; ++hh) {
            auto prr = __builtin_amdgcn_cvt_pkrtz(p[2 * hh], p[2 * hh + 1]);
            unsigned pu; __builtin_memcpy(&pu, &prr, 4);
            pk[hh] = pu;
        }
#pragma unroll
        for (int s = 0; s < 2; ++s) {    // C-frag -> B-frag(P^T), R9-verified
            auto r02 = __builtin_amdgcn_permlane32_swap(pk[4 * s + 0], pk[4 * s + 2],
                                                        false, false);
            auto r13 = __builtin_amdgcn_permlane32_swap(pk[4 * s + 1], pk[4 * s + 3],
                                                        false, false);
            H8U4 pb;
            pb.u[0] = r02[0];
            pb.u[1] = r13[0];
            pb.u[2] = r02[1];
            pb.u[3] = r13[1];
            O0 = __builtin_amdgcn_mfma_f32_32x32x16_f16(vf[s], pb.v, O0, 0, 0, 0);
            O1 = __builtin_amdgcn_mfma_f32_32x32x16_f16(vf[2 + s], pb.v, O1, 0, 0, 0);
        }
    };

    // pipeline: S double-buffer; V 1-ahead, K/hk 2-ahead, all issued BEFORE
    // the smpv that covers them (>=1 full phase load->use distance). Tail
    // clamp loads stay in-workspace and are never consumed.
    if (j0 < j1) {
        h8 kfA[4], kfB[4], vfA[4], vfB[4];
        float4 hrA[4], hrB[4];
        loadKH(j0, kfA, hrA);
        loadV(j0, vfA);
        int jp = (j0 + 1 < j1) ? j0 + 1 : j1 - 1;
        loadKH(jp, kfB, hrB);
        f32x16 Sa = qk(kfA, hrA);
        f32x16 Sb;
        int jj = j0;
        while (true) {
            // phase A: Sa/vfA ready for jj; kfB/hrB hold jj+1 (or clamp)
            Sb = qk(kfB, hrB);
            { int jn = (jj + 1 < j1) ? jj + 1 : j1 - 1; loadV(jn, vfB); }
            { int jn = (jj + 2 < j1) ? jj + 2 : j1 - 1; loadKH(jn, kfA, hrA); }
            smpv(jj, Sa, vfA);
            if (++jj >= j1) break;
            // phase B: roles swapped
            Sa = qk(kfA, hrA);
            { int jn = (jj + 1 < j1) ? jj + 1 : j1 - 1; loadV(jn, vfA); }
            { int jn = (jj + 2 < j1) ? jj + 2 : j1 - 1; loadKH(jn, kfB, hrB); }
            smpv(jj, Sb, vfB);
            if (++jj >= j1) break;
        }
    }

    // merge: wave1 publishes (m,l,O); wave0 flash-combines, normalizes, stores
    if (wv) {
#pragma unroll
        for (int r = 0; r < 16; ++r) { sm[lane][r] = O0[r]; sm[lane][16 + r] = O1[r]; }
        sm[lane][32] = ph_sum(lsum);
        sm[lane][33] = mrun;
    }
    __syncthreads();
    if (!wv) {
        float l0 = ph_sum(lsum);
        float l1 = sm[lane][32];
        float m1 = sm[lane][33];
        float m = fmaxf(mrun, m1);
        float a0 = __builtin_amdgcn_exp2f(mrun - m);
        float a1 = __builtin_amdgcn_exp2f(m1 - m);   // wave1 empty: m1=-inf -> 0
        float lt = l0 * a0 + l1 * a1;
        float inv = 1.f / lt;
        float s0 = a0 * inv, s1 = a1 * inv;
        size_t ro = fbase + (size_t)qrow * DD;
#pragma unroll
        for (int g = 0; g < 4; ++g) {
            float4 o0 = make_float4(O0[4 * g + 0] * s0 + sm[lane][4 * g + 0] * s1,
                                    O0[4 * g + 1] * s0 + sm[lane][4 * g + 1] * s1,
                                    O0[4 * g + 2] * s0 + sm[lane][4 * g + 2] * s1,
                                    O0[4 * g + 3] * s0 + sm[lane][4 * g + 3] * s1);
            *(float4*)&out[ro + 8 * g + 4 * lh] = o0;
            float4 o1 = make_float4(O1[4 * g + 0] * s0 + sm[lane][16 + 4 * g + 0] * s1,
                                    O1[4 * g + 1] * s0 + sm[lane][16 + 4 * g + 1] * s1,
                                    O1[4 * g + 2] * s0 + sm[lane][16 + 4 * g + 2] * s1,
                                    O1[4 * g + 3] * s0 + sm[lane][16 + 4 * g + 3] * s1);
            *(float4*)&out[ro + 32 + 8 * g + 4 * lh] = o1;
        }
    }
}

extern "C" void kernel_launch(void* const* d_in, const int* in_sizes, int n_in,
                              void* d_out, int out_size, void* d_ws, size_t ws_size,
                              hipStream_t stream) {
    (void)in_sizes; (void)n_in; (void)out_size; (void)ws_size;
    const float* q = (const float*)d_in[0];
    const float* k = (const float*)d_in[1];
    const float* v = (const float*)d_in[2];
    float* out = (float*)d_out;

    // ws: [hk 256KB][Ks 8MB f16][Vs 8MB f16]
    float* hk = (float*)d_ws;
    _Float16* Ks = (_Float16*)((char*)d_ws + 262144);
    _Float16* Vs = (_Float16*)((char*)d_ws + 262144 + 8388608);

    prep<<<dim3(64, 32), 64, 0, stream>>>(k, v, Ks, Vs, hk);
    rbf_attn<<<dim3(2048), 128, 0, stream>>>(q, Ks, Vs, hk, out);
}

// Round 13
// 127.326 us; speedup vs baseline: 1.0158x; 1.0034x over previous
//
#include <hip/hip_runtime.h>

#define NN 2048
#define DD 64
#define C1 0.36067376f  // 2/sqrt(D) * log2(e)
#define C1H 0.18033688f // C1/2

typedef _Float16 h8 __attribute__((ext_vector_type(8)));
typedef float f32x16 __attribute__((ext_vector_type(16)));

union H8U4 { h8 v; unsigned u[4]; };
union HU { _Float16 h; unsigned short b; };

static __device__ inline float max3f(float a, float b, float c) {
    return fmaxf(fmaxf(a, b), c);     // clang fuses to v_max3_f32
}

// v_permlane32_swap_b32 semantics (gfx950, verified on HW in R9):
//   swap(a,b): r[0] = {a[0:31] | b[0:31]};  r[1] = {a[32:63] | b[32:63]}
static __device__ inline float ph_max(float v) {
    unsigned u; __builtin_memcpy(&u, &v, 4);
    auto rr = __builtin_amdgcn_permlane32_swap(u, u, false, false);
    unsigned r0 = rr[0], r1 = rr[1];
    float a, b; __builtin_memcpy(&a, &r0, 4); __builtin_memcpy(&b, &r1, 4);
    return fmaxf(a, b);
}
static __device__ inline float ph_sum(float v) {
    unsigned u; __builtin_memcpy(&u, &v, 4);
    auto rr = __builtin_amdgcn_permlane32_swap(u, u, false, false);
    unsigned r0 = rr[0], r1 = rr[1];
    float a, b; __builtin_memcpy(&a, &r0, 4); __builtin_memcpy(&b, &r1, 4);
    return a + b;
}

// ---- prep v2: LDS-free, 256-thread blocks (4 tiles), frag-major swizzles ----
// Ks[bh][jj][c][lh][ln]{8}  = K[32jj+ln][16c+8lh+0..7]          (A-frag order)
// Vs[bh][jj][o][c][lh][ln]{8}= V[32jj+16c+8lh+j][32o+ln]        (V^T A-frag order)
// hk2[bh][n] = f16 pair {hi,lo}: hi+lo == -C1H*||k_n||^2 (double-f16 exact bias)
// V^T frags via DIRECT coalesced column loads (lanes ln=0..31 span a contiguous
// 128B row segment) -- no LDS, no syncthreads, no scalar ds_read_u16.
__global__ __launch_bounds__(256) void prep(const float* __restrict__ k,
                                            const float* __restrict__ v,
                                            _Float16* __restrict__ Ks,
                                            _Float16* __restrict__ Vs,
                                            unsigned* __restrict__ hk2) {
    const int bx = blockIdx.x, bh = blockIdx.y;
    const int tid = threadIdx.x;
    const int wv = tid >> 6, lane = tid & 63;
    const int jj = bx * 4 + wv;
    const int ln = lane & 31, lh = lane >> 5;
    const size_t ibase = (size_t)bh * NN * DD + (size_t)jj * 32 * DD;

    { // K frags + row sumsq (lh halves cover complementary d-ranges)
        const float* kr = k + ibase + (size_t)ln * DD;
        float s = 0.f;
#pragma unroll
        for (int c = 0; c < 4; ++c) {
            float4 a = *(const float4*)&kr[16 * c + 8 * lh];
            float4 b = *(const float4*)&kr[16 * c + 8 * lh + 4];
            h8 o = {(_Float16)a.x, (_Float16)a.y, (_Float16)a.z, (_Float16)a.w,
                    (_Float16)b.x, (_Float16)b.y, (_Float16)b.z, (_Float16)b.w};
            *(h8*)&Ks[((size_t)bh * 16384 + jj * 256 + c * 64 + lh * 32 + ln) * 8] = o;
            s += a.x*a.x + a.y*a.y + a.z*a.z + a.w*a.w
               + b.x*b.x + b.y*b.y + b.z*b.z + b.w*b.w;
        }
        s += __shfl_xor(s, 32);
        if (lh == 0) {
            float vv = -C1H * s;
            HU hi; hi.h = (_Float16)vv;
            HU lo; lo.h = (_Float16)(vv - (float)hi.h);
            hk2[bh * NN + jj * 32 + ln] = (unsigned)hi.b | ((unsigned)lo.b << 16);
        }
    }

    // V^T frags: 8 coalesced dword column loads per frag, pack, store
#pragma unroll
    for (int oc = 0; oc < 4; ++oc) {
        int o = oc >> 1, c = oc & 1;
        const float* vb = v + ibase + (size_t)(16 * c + 8 * lh) * DD + 32 * o + ln;
        h8 r;
#pragma unroll
        for (int jx = 0; jx < 8; ++jx) r[jx] = (_Float16)vb[(size_t)jx * DD];
        *(h8*)&Vs[((size_t)bh * 16384 + jj * 256 + o * 128 + c * 64 + lh * 32 + ln) * 8] = r;
    }
}

// ---- main: flash RBF, key-split-2, pipeline + XCD swizzle + MFMA-bias ----
// QK = 5 MFMAs: chunk4 carries the key-norm bias as a double-f16 pair
// (A=[hi,lo,0..] for lh=0 lanes, B=[1,1,0..]) -> S = full shifted logit with
// ZERO-init accumulator and no hk on the load-init chain (exact in f32 accum).
// 1D grid n: bh=(n&7)*4+((n>>3)&3), qt=63-(n>>5) (XCD L2 locality + LPT).
// Per phase: qk(next S) -> issue V(jj+1), K/bias(jj+2) -> smpv(jj).
// REGISTER CLASS: 2 waves/SIMD. Sentinels: WRITE_SIZE 16.4 MB, VGPR ~70.
__global__ __launch_bounds__(128, 2) void rbf_attn(
    const float* __restrict__ q, const _Float16* __restrict__ Ks,
    const _Float16* __restrict__ Vs, const unsigned* __restrict__ hk2,
    float* __restrict__ out)
{
    __shared__ float sm[64][34];         // wave1: O (32 f32/lane) + l + m
    const int tid = threadIdx.x;
    const int n = blockIdx.x;
    const int bh = (n & 7) * 4 + ((n >> 3) & 3);
    const int qt = 63 - (n >> 5);        // LPT: heavy q-tiles dispatch first
    const int wv = tid >> 6, lane = tid & 63;
    const int ln = lane & 31, lh = lane >> 5;
    const int qrow = qt * 32 + ln;
    const size_t fbase = (size_t)bh * NN * DD;

    // Q B-frags pre-scaled by C1 + constant bias B-frag (k=0,1 ones, lh=0 only)
    h8 qf[4];
    H8U4 qc4;
    {
        const float* qr = q + fbase + (size_t)qrow * DD;
#pragma unroll
        for (int c = 0; c < 4; ++c) {
            float4 a = *(const float4*)&qr[16 * c + 8 * lh];
            float4 b = *(const float4*)&qr[16 * c + 8 * lh + 4];
            qf[c] = h8{(_Float16)(C1 * a.x), (_Float16)(C1 * a.y),
                       (_Float16)(C1 * a.z), (_Float16)(C1 * a.w),
                       (_Float16)(C1 * b.x), (_Float16)(C1 * b.y),
                       (_Float16)(C1 * b.z), (_Float16)(C1 * b.w)};
        }
        qc4.u[0] = lh ? 0u : 0x3C003C00u;   // f16 {1,1} at k-slots 0,1
        qc4.u[1] = 0u; qc4.u[2] = 0u; qc4.u[3] = 0u;
    }

    const _Float16* Ksb = Ks + (size_t)bh * 131072;
    const _Float16* Vsb = Vs + (size_t)bh * 131072;
    const unsigned* hk2b = hk2 + bh * NN;
    const int klq = (lh * 32 + ln) * 8;  // element offset of this lane's frag

    f32x16 O0, O1;
#pragma unroll
    for (int r = 0; r < 16; ++r) { O0[r] = 0.f; O1[r] = 0.f; }
    float lsum = 0.f, mrun = -INFINITY;

    const int T = qt + 1;                // key tiles for this q-tile
    const int half = (T + 1) >> 1;       // wave0 gets ceil (wave1 pays diag mask)
    const int j0 = wv ? half : 0;
    const int j1 = wv ? T : half;

    auto loadKB = [&](int jj, h8 (&kf)[4], unsigned& bias) {
        const _Float16* kp = Ksb + (size_t)jj * 2048 + klq;
#pragma unroll
        for (int c = 0; c < 4; ++c) kf[c] = *(const h8*)(kp + c * 512);
        bias = hk2b[jj * 32 + ln];       // {hi,lo} f16 pair per key row
    };
    auto loadV = [&](int jj, h8 (&vf)[4]) {
        const _Float16* vp = Vsb + (size_t)jj * 2048 + klq;
#pragma unroll
        for (int oc = 0; oc < 4; ++oc)
            vf[oc] = *(const h8*)(vp + (oc >> 1) * 1024 + (oc & 1) * 512);
    };

    // S = bias + K.(C1*Q): zero-init acc, bias via chunk4 MFMA (exact in f32)
    auto qk = [&](const h8 (&kf)[4], unsigned bias) {
        f32x16 S;
#pragma unroll
        for (int r = 0; r < 16; ++r) S[r] = 0.f;
        H8U4 k4;
        k4.u[0] = lh ? 0u : bias;
        k4.u[1] = 0u; k4.u[2] = 0u; k4.u[3] = 0u;
        S = __builtin_amdgcn_mfma_f32_32x32x16_f16(k4.v, qc4.v, S, 0, 0, 0);
#pragma unroll
        for (int c = 0; c < 4; ++c)
            S = __builtin_amdgcn_mfma_f32_32x32x16_f16(kf[c], qf[c], S, 0, 0, 0);
        return S;
    };

    // softmax + PV for tile jj, consuming precomputed S and prefetched vf
    auto smpv = [&](int jj, const f32x16& S, const h8 (&vf)[4]) {
        const bool diag = (jj == qt);
        float x[16];
#pragma unroll
        for (int r = 0; r < 16; ++r) {
            float xv = S[r];
            if (diag) {
                int keyloc = (r & 3) + 8 * (r >> 2) + 4 * lh;
                if (keyloc > ln) xv = -INFINITY;
            }
            x[r] = xv;
        }
        float m0 = max3f(x[0], x[1], x[2]);
        float m1 = max3f(x[3], x[4], x[5]);
        float m2 = max3f(x[6], x[7], x[8]);
        float m3 = max3f(x[9], x[10], x[11]);
        float m4 = max3f(x[12], x[13], x[14]);
        float mt = max3f(max3f(m0, m1, m2), fmaxf(m3, m4), x[15]);
        mt = ph_max(mt);
        float mnew = fmaxf(mrun, mt);
        float alpha = __builtin_amdgcn_exp2f(mrun - mnew);
        mrun = mnew;
        float p[16], ps;
#pragma unroll
        for (int r = 0; r < 16; ++r) p[r] = __builtin_amdgcn_exp2f(x[r] - mnew);
        ps = (((p[0] + p[1]) + (p[2] + p[3])) + ((p[4] + p[5]) + (p[6] + p[7])))
           + (((p[8] + p[9]) + (p[10] + p[11])) + ((p[12] + p[13]) + (p[14] + p[15])));
        lsum = fmaf(lsum, alpha, ps);
#pragma unroll
        for (int r = 0; r < 16; ++r) { O0[r] *= alpha; O1[r] *= alpha; }

        unsigned pk[8];
#pragma unroll
        for (int hh = 0; hh < 8; ++hh) {
            auto prr = __builtin_amdgcn_cvt_pkrtz(p[2 * hh], p[2 * hh + 1]);
            unsigned pu; __builtin_memcpy(&pu, &prr, 4);
            pk[hh] = pu;
        }
#pragma unroll
        for (int s = 0; s < 2; ++s) {    // C-frag -> B-frag(P^T), R9-verified
            auto r02 = __builtin_amdgcn_permlane32_swap(pk[4 * s + 0], pk[4 * s + 2],
                                                        false, false);
            auto r13 = __builtin_amdgcn_permlane32_swap(pk[4 * s + 1], pk[4 * s + 3],
                                                        false, false);
            H8U4 pb;
            pb.u[0] = r02[0];
            pb.u[1] = r13[0];
            pb.u[2] = r02[1];
            pb.u[3] = r13[1];
            O0 = __builtin_amdgcn_mfma_f32_32x32x16_f16(vf[s], pb.v, O0, 0, 0, 0);
            O1 = __builtin_amdgcn_mfma_f32_32x32x16_f16(vf[2 + s], pb.v, O1, 0, 0, 0);
        }
    };

    // pipeline: S double-buffer; V 1-ahead, K/bias 2-ahead, all issued BEFORE
    // the smpv that covers them. Tail clamp loads stay in-workspace.
    if (j0 < j1) {
        h8 kfA[4], kfB[4], vfA[4], vfB[4];
        unsigned biA, biB;
        loadKB(j0, kfA, biA);
        loadV(j0, vfA);
        int jp = (j0 + 1 < j1) ? j0 + 1 : j1 - 1;
        loadKB(jp, kfB, biB);
        f32x16 Sa = qk(kfA, biA);
        f32x16 Sb;
        int jj = j0;
        while (true) {
            // phase A: Sa/vfA ready for jj; kfB/biB hold jj+1 (or clamp)
            Sb = qk(kfB, biB);
            { int jn = (jj + 1 < j1) ? jj + 1 : j1 - 1; loadV(jn, vfB); }
            { int jn = (jj + 2 < j1) ? jj + 2 : j1 - 1; loadKB(jn, kfA, biA); }
            smpv(jj, Sa, vfA);
            if (++jj >= j1) break;
            // phase B: roles swapped
            Sa = qk(kfA, biA);
            { int jn = (jj + 1 < j1) ? jj + 1 : j1 - 1; loadV(jn, vfA); }
            { int jn = (jj + 2 < j1) ? jj + 2 : j1 - 1; loadKB(jn, kfB, biB); }
            smpv(jj, Sb, vfB);
            if (++jj >= j1) break;
        }
    }

    // merge: wave1 publishes (m,l,O); wave0 flash-combines, normalizes, stores
    if (wv) {
#pragma unroll
        for (int r = 0; r < 16; ++r) { sm[lane][r] = O0[r]; sm[lane][16 + r] = O1[r]; }
        sm[lane][32] = ph_sum(lsum);
        sm[lane][33] = mrun;
    }
    __syncthreads();
    if (!wv) {
        float l0 = ph_sum(lsum);
        float l1 = sm[lane][32];
        float m1 = sm[lane][33];
        float m = fmaxf(mrun, m1);
        float a0 = __builtin_amdgcn_exp2f(mrun - m);
        float a1 = __builtin_amdgcn_exp2f(m1 - m);   // wave1 empty: m1=-inf -> 0
        float lt = l0 * a0 + l1 * a1;
        float inv = 1.f / lt;
        float s0 = a0 * inv, s1 = a1 * inv;
        size_t ro = fbase + (size_t)qrow * DD;
#pragma unroll
        for (int g = 0; g < 4; ++g) {
            float4 o0 = make_float4(O0[4 * g + 0] * s0 + sm[lane][4 * g + 0] * s1,
                                    O0[4 * g + 1] * s0 + sm[lane][4 * g + 1] * s1,
                                    O0[4 * g + 2] * s0 + sm[lane][4 * g + 2] * s1,
                                    O0[4 * g + 3] * s0 + sm[lane][4 * g + 3] * s1);
            *(float4*)&out[ro + 8 * g + 4 * lh] = o0;
            float4 o1 = make_float4(O1[4 * g + 0] * s0 + sm[lane][16 + 4 * g + 0] * s1,
                                    O1[4 * g + 1] * s0 + sm[lane][16 + 4 * g + 1] * s1,
                                    O1[4 * g + 2] * s0 + sm[lane][16 + 4 * g + 2] * s1,
                                    O1[4 * g + 3] * s0 + sm[lane][16 + 4 * g + 3] * s1);
            *(float4*)&out[ro + 32 + 8 * g + 4 * lh] = o1;
        }
    }
}

extern "C" void kernel_launch(void* const* d_in, const int* in_sizes, int n_in,
                              void* d_out, int out_size, void* d_ws, size_t ws_size,
                              hipStream_t stream) {
    (void)in_sizes; (void)n_in; (void)out_size; (void)ws_size;
    const float* q = (const float*)d_in[0];
    const float* k = (const float*)d_in[1];
    const float* v = (const float*)d_in[2];
    float* out = (float*)d_out;

    // ws: [hk2 256KB][Ks 8MB f16][Vs 8MB f16]
    unsigned* hk2 = (unsigned*)d_ws;
    _Float16* Ks = (_Float16*)((char*)d_ws + 262144);
    _Float16* Vs = (_Float16*)((char*)d_ws + 262144 + 8388608);

    prep<<<dim3(16, 32), 256, 0, stream>>>(k, v, Ks, Vs, hk2);
    rbf_attn<<<dim3(2048), 128, 0, stream>>>(q, Ks, Vs, hk2, out);
}